// Round 1
// baseline (466.319 us; speedup 1.0000x reference)
//
#include <hip/hip_runtime.h>

#define F_IN  256
#define F_OUT 32
#define ROWS_PER_BLOCK 8

// ---------- edge-index dtype detection ----------
// If edge_index was materialized as int64 (little-endian, values >= 0 and
// < 2^31), every odd 32-bit word is zero. For int32 random indices the odds
// of 32 consecutive odd words all being zero are ~0. Flag: 1 = int64 layout.
__global__ void k_detect(const int* __restrict__ ei, int* __restrict__ flag) {
    if (blockIdx.x == 0 && threadIdx.x == 0) {
        int o = 0;
        for (int i = 1; i < 64; i += 2) o |= ei[i];
        *flag = (o == 0) ? 1 : 0;
    }
}

__device__ __forceinline__ int load_idx(const int* __restrict__ ei, int i, int mode64) {
    return mode64 ? ei[2 * i] : ei[i];
}

// ---------- degree ----------
__global__ void k_deg_init(float* __restrict__ deg, int N) {
    int i = blockIdx.x * blockDim.x + threadIdx.x;
    if (i < N) deg[i] = 1.0f;  // self-loop
}

__global__ void k_deg_count(const int* __restrict__ ei, float* __restrict__ deg,
                            const int* __restrict__ flag, int E, int N) {
    int e = blockIdx.x * blockDim.x + threadIdx.x;
    if (e < E) {
        int m64 = *flag;
        int d = load_idx(ei, E + e, m64);  // dst row of edge_index
        if ((unsigned)d < (unsigned)N) atomicAdd(&deg[d], 1.0f);
    }
}

__global__ void k_dinv(const float* __restrict__ deg, float* __restrict__ dinv, int N) {
    int i = blockIdx.x * blockDim.x + threadIdx.x;
    if (i < N) dinv[i] = rsqrtf(deg[i]);  // deg >= 1 always
}

// ---------- h = x @ W, fused: hs = h*dinv (to ws), out = b + hs*dinv ----------
__global__ __launch_bounds__(256) void k_gemm(const float* __restrict__ x,
                                              const float* __restrict__ W,
                                              const float* __restrict__ b,
                                              const float* __restrict__ dinv,
                                              float* __restrict__ hs,
                                              float* __restrict__ out, int N) {
    __shared__ __align__(16) float sW[F_IN * F_OUT];            // 32 KB
    __shared__ __align__(16) float sx[ROWS_PER_BLOCK * F_IN];   // 8 KB
    const int tid = threadIdx.x;
    const int row0 = blockIdx.x * ROWS_PER_BLOCK;

    // cooperative load of W (8192 floats / 256 threads = 32 each)
    #pragma unroll
    for (int i = 0; i < (F_IN * F_OUT) / 256; ++i)
        sW[i * 256 + tid] = W[i * 256 + tid];

    // cooperative load of 8 x-rows (2048 floats = 512 float4)
    #pragma unroll
    for (int i = 0; i < (ROWS_PER_BLOCK * F_IN) / (256 * 4); ++i) {
        int flat4 = i * 256 + tid;              // float4 index within tile
        int grow  = row0 + (flat4 * 4) / F_IN;  // global row this float4 belongs to
        float4 v = make_float4(0.f, 0.f, 0.f, 0.f);
        if (grow < N)
            v = ((const float4*)(x + (size_t)row0 * F_IN))[flat4];
        ((float4*)sx)[flat4] = v;
    }
    __syncthreads();

    const int row = tid >> 5;   // 0..7
    const int f   = tid & 31;   // 0..31
    const int grow = row0 + row;

    float sum = 0.f;
    const float4* sxr = (const float4*)(sx + row * F_IN);
    #pragma unroll
    for (int k4 = 0; k4 < F_IN / 4; ++k4) {
        float4 xv = sxr[k4];
        sum += xv.x * sW[(k4 * 4 + 0) * F_OUT + f];
        sum += xv.y * sW[(k4 * 4 + 1) * F_OUT + f];
        sum += xv.z * sW[(k4 * 4 + 2) * F_OUT + f];
        sum += xv.w * sW[(k4 * 4 + 3) * F_OUT + f];
    }

    if (grow < N) {
        float di = dinv[grow];
        float h_scaled = sum * di;                    // hs = h * dinv[src-side]
        hs[(size_t)grow * F_OUT + f] = h_scaled;
        out[(size_t)grow * F_OUT + f] = b[f] + h_scaled * di;  // bias + self-loop
    }
}

// ---------- edge scatter: out[dst] += hs[src] * dinv[dst] ----------
__global__ __launch_bounds__(256) void k_scatter(const int* __restrict__ ei,
                                                 const float* __restrict__ hs,
                                                 const float* __restrict__ dinv,
                                                 float* __restrict__ out,
                                                 const int* __restrict__ flag,
                                                 int E, int N) {
    long long gid = (long long)blockIdx.x * blockDim.x + threadIdx.x;
    int e = (int)(gid >> 5);
    int f = (int)(gid & 31);
    if (e < E) {
        int m64 = *flag;
        int s = load_idx(ei, e, m64);
        int d = load_idx(ei, E + e, m64);
        if ((unsigned)s < (unsigned)N && (unsigned)d < (unsigned)N) {
            float v = hs[(size_t)s * F_OUT + f] * dinv[d];
            atomicAdd(&out[(size_t)d * F_OUT + f], v);
        }
    }
}

extern "C" void kernel_launch(void* const* d_in, const int* in_sizes, int n_in,
                              void* d_out, int out_size, void* d_ws, size_t ws_size,
                              hipStream_t stream) {
    const float* x  = (const float*)d_in[0];
    const int*   ei = (const int*)d_in[1];
    const float* W  = (const float*)d_in[2];
    const float* b  = (const float*)d_in[3];
    float* out = (float*)d_out;

    const int N = in_sizes[0] / F_IN;   // 100000
    const int E = in_sizes[1] / 2;      // 1600000 (element count is 2E for int32 or int64)

    float* hs   = (float*)d_ws;                 // N * 32 floats
    float* deg  = hs + (size_t)N * F_OUT;       // N floats
    float* dinv = deg + N;                      // N floats
    int*   flag = (int*)(dinv + N);             // 1 int

    k_detect<<<1, 64, 0, stream>>>(ei, flag);
    k_deg_init<<<(N + 255) / 256, 256, 0, stream>>>(deg, N);
    k_deg_count<<<(E + 255) / 256, 256, 0, stream>>>(ei, deg, flag, E, N);
    k_dinv<<<(N + 255) / 256, 256, 0, stream>>>(deg, dinv, N);
    k_gemm<<<(N + ROWS_PER_BLOCK - 1) / ROWS_PER_BLOCK, 256, 0, stream>>>(
        x, W, b, dinv, hs, out, N);
    long long scatter_threads = (long long)E * F_OUT;
    k_scatter<<<(int)((scatter_threads + 255) / 256), 256, 0, stream>>>(
        ei, hs, dinv, out, flag, E, N);
}

// Round 2
// 462.972 us; speedup vs baseline: 1.0072x; 1.0072x over previous
//
#include <hip/hip_runtime.h>

#define F_IN  256
#define F_OUT 32

// ---------- edge-index dtype detection ----------
// int64 little-endian with values < 2^31 => every odd 32-bit word is zero.
__global__ void k_detect(const int* __restrict__ ei, int* __restrict__ flag) {
    if (blockIdx.x == 0 && threadIdx.x == 0) {
        int o = 0;
        for (int i = 1; i < 64; i += 2) o |= ei[i];
        *flag = (o == 0) ? 1 : 0;
    }
}

__device__ __forceinline__ int load_idx(const int* __restrict__ ei, int i, int mode64) {
    return mode64 ? ei[2 * i] : ei[i];
}

// ---------- CSR build ----------
__global__ void k_zero(int* __restrict__ cnt, int N) {
    int i = blockIdx.x * blockDim.x + threadIdx.x;
    if (i < N) cnt[i] = 0;
}

__global__ void k_count(const int* __restrict__ ei, int* __restrict__ cnt,
                        const int* __restrict__ flag, int E, int N) {
    int e = blockIdx.x * blockDim.x + threadIdx.x;
    if (e < E) {
        int m64 = *flag;
        int d = load_idx(ei, E + e, m64);
        if ((unsigned)d < (unsigned)N) atomicAdd(&cnt[d], 1);
    }
}

// block-level exclusive scan of cnt (chunks of 256) -> cursor(local excl), blocksum
__global__ __launch_bounds__(256) void k_scan1(const int* __restrict__ cnt,
                                               int* __restrict__ cursor,
                                               int* __restrict__ blocksum, int N) {
    __shared__ int sd[256];
    int t = threadIdx.x;
    int i = blockIdx.x * 256 + t;
    int v = (i < N) ? cnt[i] : 0;
    sd[t] = v;
    __syncthreads();
    #pragma unroll
    for (int off = 1; off < 256; off <<= 1) {
        int add = (t >= off) ? sd[t - off] : 0;
        __syncthreads();
        sd[t] += add;
        __syncthreads();
    }
    if (i < N) cursor[i] = sd[t] - v;          // exclusive local
    if (t == 255) blocksum[blockIdx.x] = sd[t]; // inclusive block total
}

// single-block exclusive scan of blocksum (in place), nb <= 512
__global__ __launch_bounds__(512) void k_scan2(int* __restrict__ blocksum, int nb) {
    __shared__ int sd[512];
    int t = threadIdx.x;
    int v = (t < nb) ? blocksum[t] : 0;
    sd[t] = v;
    __syncthreads();
    #pragma unroll
    for (int off = 1; off < 512; off <<= 1) {
        int add = (t >= off) ? sd[t - off] : 0;
        __syncthreads();
        sd[t] += add;
        __syncthreads();
    }
    if (t < nb) blocksum[t] = sd[t] - v;       // exclusive
}

// finalize: cursor = global exclusive offset; dinv = rsqrt(deg) with self-loop
__global__ void k_scan3(int* __restrict__ cursor, const int* __restrict__ blocksum,
                        const int* __restrict__ cnt, float* __restrict__ dinv, int N) {
    int i = blockIdx.x * blockDim.x + threadIdx.x;
    if (i < N) {
        cursor[i] += blocksum[i >> 8];
        dinv[i] = rsqrtf((float)(cnt[i] + 1));
    }
}

// bucket fill: csr[pos] = src. After this, cursor[d] = end offset of d's bucket.
__global__ void k_fill(const int* __restrict__ ei, int* __restrict__ cursor,
                       int* __restrict__ csr, const int* __restrict__ flag,
                       int E, int N) {
    int e = blockIdx.x * blockDim.x + threadIdx.x;
    if (e < E) {
        int m64 = *flag;
        int s = load_idx(ei, e, m64);
        int d = load_idx(ei, E + e, m64);
        if ((unsigned)d < (unsigned)N) {
            int pos = atomicAdd(&cursor[d], 1);
            csr[pos] = s;
        }
    }
}

// ---------- register-tiled GEMM: hs[n][f] = (x@W)[n][f] * dinv[n] ----------
// block: 256 threads -> 128 rows x 32 cols; thread: 4 rows x 4 cols
#define KC 64
#define LDP 68  // padded leading dim (floats), 16B-aligned, conflict-free
__global__ __launch_bounds__(256) void k_gemm(const float* __restrict__ x,
                                              const float* __restrict__ W,
                                              const float* __restrict__ dinv,
                                              float* __restrict__ hs, int N) {
    __shared__ __align__(16) float sx[128 * LDP];   // 34.8 KB
    __shared__ __align__(16) float sWt[F_OUT * LDP]; // 8.7 KB, transposed [f][k]
    const int tid = threadIdx.x;
    const int fbase = tid & 7;    // cols: fbase + 8m
    const int rbase = tid >> 3;   // rows: rbase + 32j
    const int row0 = blockIdx.x * 128;

    float acc[4][4];
    #pragma unroll
    for (int j = 0; j < 4; ++j)
        #pragma unroll
        for (int m = 0; m < 4; ++m) acc[j][m] = 0.f;

    for (int c = 0; c < F_IN / KC; ++c) {
        // stage x: 128 rows x KC floats = 2048 float4
        #pragma unroll
        for (int i = 0; i < 8; ++i) {
            int flat4 = i * 256 + tid;
            int r = flat4 >> 4;       // 16 float4 per row
            int q = flat4 & 15;
            float4 v = make_float4(0.f, 0.f, 0.f, 0.f);
            if (row0 + r < N)
                v = ((const float4*)x)[(size_t)(row0 + r) * (F_IN / 4) + c * (KC / 4) + q];
            *(float4*)(sx + r * LDP + q * 4) = v;
        }
        // stage W transposed: KC x 32 floats
        #pragma unroll
        for (int i = 0; i < 8; ++i) {
            int flat = i * 256 + tid;
            int k = flat >> 5;
            int f = flat & 31;
            sWt[f * LDP + k] = W[(size_t)(c * KC + k) * F_OUT + f];
        }
        __syncthreads();

        #pragma unroll 4
        for (int k0 = 0; k0 < KC; k0 += 4) {
            float4 wv[4], xv[4];
            #pragma unroll
            for (int m = 0; m < 4; ++m)
                wv[m] = *(const float4*)(sWt + (fbase + 8 * m) * LDP + k0);
            #pragma unroll
            for (int j = 0; j < 4; ++j)
                xv[j] = *(const float4*)(sx + (rbase + 32 * j) * LDP + k0);
            #pragma unroll
            for (int j = 0; j < 4; ++j)
                #pragma unroll
                for (int m = 0; m < 4; ++m)
                    acc[j][m] += xv[j].x * wv[m].x + xv[j].y * wv[m].y +
                                 xv[j].z * wv[m].z + xv[j].w * wv[m].w;
        }
        __syncthreads();
    }

    #pragma unroll
    for (int j = 0; j < 4; ++j) {
        int row = row0 + rbase + 32 * j;
        if (row < N) {
            float di = dinv[row];
            #pragma unroll
            for (int m = 0; m < 4; ++m)
                hs[(size_t)row * F_OUT + fbase + 8 * m] = acc[j][m] * di;
        }
    }
}

// ---------- gather: out[d] = b + dinv[d] * (hs[d] + sum_{incoming} hs[s]) ----------
__global__ __launch_bounds__(256) void k_gather(const int* __restrict__ csr,
                                                const int* __restrict__ cursor,
                                                const int* __restrict__ cnt,
                                                const float* __restrict__ hs,
                                                const float* __restrict__ dinv,
                                                const float* __restrict__ b,
                                                float* __restrict__ out, int N) {
    int n = blockIdx.x * 8 + (threadIdx.x >> 5);
    int f = threadIdx.x & 31;
    if (n >= N) return;
    int c = cnt[n];
    int end = cursor[n];        // after fill, cursor = bucket end
    int j = end - c;
    float acc = hs[(size_t)n * F_OUT + f];   // self-loop term
    // prefetch index one iteration ahead to overlap the two dependent loads
    int s_next = (j < end) ? csr[j] : 0;
    while (j < end) {
        int s = s_next;
        ++j;
        if (j < end) s_next = csr[j];
        acc += hs[(size_t)s * F_OUT + f];
    }
    out[(size_t)n * F_OUT + f] = b[f] + dinv[n] * acc;
}

extern "C" void kernel_launch(void* const* d_in, const int* in_sizes, int n_in,
                              void* d_out, int out_size, void* d_ws, size_t ws_size,
                              hipStream_t stream) {
    const float* x  = (const float*)d_in[0];
    const int*   ei = (const int*)d_in[1];
    const float* W  = (const float*)d_in[2];
    const float* b  = (const float*)d_in[3];
    float* out = (float*)d_out;

    const int N = in_sizes[0] / F_IN;   // 100000
    const int E = in_sizes[1] / 2;      // 1600000

    // workspace layout
    float* hs     = (float*)d_ws;                    // N*32 floats (12.8 MB)
    int*   cnt    = (int*)(hs + (size_t)N * F_OUT);  // N ints
    int*   cursor = cnt + N;                         // N ints
    float* dinv   = (float*)(cursor + N);            // N floats
    int*   bsum   = (int*)(dinv + N);                // 512 ints
    int*   flag   = bsum + 512;                      // 1 int
    int*   csr    = flag + 1;                        // E ints (6.4 MB)

    const int nb = (N + 255) / 256;   // scan blocks (391 <= 512)

    k_detect<<<1, 64, 0, stream>>>(ei, flag);
    k_zero  <<<nb, 256, 0, stream>>>(cnt, N);
    k_count <<<(E + 255) / 256, 256, 0, stream>>>(ei, cnt, flag, E, N);
    k_scan1 <<<nb, 256, 0, stream>>>(cnt, cursor, bsum, N);
    k_scan2 <<<1, 512, 0, stream>>>(bsum, nb);
    k_scan3 <<<nb, 256, 0, stream>>>(cursor, bsum, cnt, dinv, N);
    k_fill  <<<(E + 255) / 256, 256, 0, stream>>>(ei, cursor, csr, flag, E, N);
    k_gemm  <<<(N + 127) / 128, 256, 0, stream>>>(x, W, dinv, hs, N);
    k_gather<<<(N + 7) / 8, 256, 0, stream>>>(csr, cursor, cnt, hs, dinv, b, out, N);
}